// Round 4
// baseline (1717.625 us; speedup 1.0000x reference)
//
#include <hip/hip_runtime.h>
#include <hip/hip_bf16.h>

typedef __hip_bfloat16 bf16;
typedef unsigned short u16;
typedef __attribute__((ext_vector_type(8))) short bf16x8;   // 8 bf16 in 4 VGPRs (MFMA A/B frag)
typedef __attribute__((ext_vector_type(4))) float f32x4;    // MFMA C/D frag

#define N_NODES 100000
#define N_EDGES 1600000
#define B_SHIFT 7
#define B_MASK 127
#define NBUCK 782           // ceil(N_NODES/128), bucket = dst >> 7
#define NBLK 256            // edge-chunk blocks for hist/scatter (q1/q2/q4)

static __device__ __forceinline__ u16 f2bf(float x) {
    bf16 h = (bf16)x;
    return *reinterpret_cast<u16*>(&h);
}
static __device__ __forceinline__ float bf2f(u16 b) {
    unsigned u = ((unsigned)b) << 16;
    return __uint_as_float(u);
}

// ================= Bucket sort (q1..q4) =================
// Two-level deterministic scatter: per-(block,bucket) contiguous runs keep
// WRITE_SIZE ~2x data size (round-2 lesson: random 4B global scatter = 16x amp).
// p4/csr/rowptr are GONE: gathers consume bucket-contiguous `packed` directly,
// accumulating per-bucket in LDS (round-2 proved within-row order is irrelevant).

__global__ __launch_bounds__(512) void q1_hist(const int* __restrict__ dst,
                                               int* __restrict__ bh, int nE) {
    __shared__ int hist[NBUCK];
    int t = threadIdx.x, b = blockIdx.x;
    for (int i = t; i < NBUCK; i += 512) hist[i] = 0;
    __syncthreads();
    int chunk = (nE + NBLK - 1) / NBLK;
    int lo = b * chunk, hi = min(nE, lo + chunk);
    for (int e = lo + t; e < hi; e += 512) atomicAdd(&hist[dst[e] >> B_SHIFT], 1);
    __syncthreads();
    for (int i = t; i < NBUCK; i += 512) bh[b * NBUCK + i] = hist[i];
}

// exclusive column scan over the NBLK chunk-blocks (threads = NBLK = 256)
__global__ __launch_bounds__(256) void q2_colscan(int* __restrict__ bh,
                                                  int* __restrict__ total) {
    __shared__ int s[256];
    int i = blockIdx.x;       // bucket
    int b = threadIdx.x;      // chunk-block
    int val = bh[b * NBUCK + i];
    s[b] = val;
    __syncthreads();
    for (int off = 1; off < 256; off <<= 1) {
        int x = (b >= off) ? s[b - off] : 0;
        __syncthreads();
        if (b >= off) s[b] += x;
        __syncthreads();
    }
    bh[b * NBUCK + i] = s[b] - val;        // exclusive over blocks
    if (b == 255) total[i] = s[255];
}

__global__ __launch_bounds__(1024) void q3_scan(const int* __restrict__ total,
                                                int* __restrict__ bucket_base, int nE) {
    __shared__ int s[1024];
    int t = threadIdx.x;
    int val = (t < NBUCK) ? total[t] : 0;
    s[t] = val;
    __syncthreads();
    for (int off = 1; off < 1024; off <<= 1) {
        int x = (t >= off) ? s[t - off] : 0;
        __syncthreads();
        if (t >= off) s[t] += x;
        __syncthreads();
    }
    if (t < NBUCK) bucket_base[t] = s[t] - val;
    if (t == 0) bucket_base[NBUCK] = nE;
}

__global__ __launch_bounds__(512) void q4_scatter(const int* __restrict__ src,
                                                  const int* __restrict__ dst,
                                                  const int* __restrict__ bh,
                                                  const int* __restrict__ bucket_base,
                                                  unsigned int* __restrict__ packed, int nE) {
    __shared__ int cur[NBUCK];
    int t = threadIdx.x, b = blockIdx.x;
    for (int i = t; i < NBUCK; i += 512)
        cur[i] = bucket_base[i] + bh[b * NBUCK + i];
    __syncthreads();
    int chunk = (nE + NBLK - 1) / NBLK;
    int lo = b * chunk, hi = min(nE, lo + chunk);
    for (int e = lo + t; e < hi; e += 512) {
        int d = dst[e];
        int pos = atomicAdd(&cur[d >> B_SHIFT], 1);
        packed[pos] = ((unsigned int)(d & B_MASK) << 17) | (unsigned int)src[e];
    }
}

// ================= Weight pre-fragmentation for MFMA =================
// W' = [Ws | Wn] combined, [64 k][2*ncol n], split into bf16 hi/lo:
//   w = wh + wl  (3-pass GEMM ah@wh + al@wh + ah@wl -> f32-grade accuracy).
// Fragment order for mfma_f32_16x16x32_bf16 B-operand; see round-0 notes.

__global__ __launch_bounds__(256) void k_wprep(const float* __restrict__ Ws0, const float* __restrict__ Wn0,
                                               const float* __restrict__ Ws1, const float* __restrict__ Wn1,
                                               const float* __restrict__ Ws2, const float* __restrict__ Wn2,
                                               u16* __restrict__ wf0, u16* __restrict__ wf1,
                                               u16* __restrict__ wf2) {
    int id = blockIdx.x * 256 + threadIdx.x;   // 0..9215
    const float *Ws, *Wn;
    u16* wf;
    int ncol, nfc;
    if (id < 4096)       { Ws = Ws0; Wn = Wn0; wf = wf0; ncol = 64; nfc = 8; }
    else if (id < 8192)  { id -= 4096; Ws = Ws1; Wn = Wn1; wf = wf1; ncol = 64; nfc = 8; }
    else if (id < 9216)  { id -= 8192; Ws = Ws2; Wn = Wn2; wf = wf2; ncol = 16; nfc = 2; }
    else return;
    int kp = id / (2 * ncol);       // 0..31 k-pair
    int n  = id % (2 * ncol);
    int k  = kp * 2;
    float w0 = (n < ncol) ? Ws[k * ncol + n]       : Wn[k * ncol + (n - ncol)];
    float w1 = (n < ncol) ? Ws[(k + 1) * ncol + n] : Wn[(k + 1) * ncol + (n - ncol)];
    u16 h0 = f2bf(w0), h1 = f2bf(w1);
    u16 l0 = f2bf(w0 - bf2f(h0)), l1 = f2bf(w1 - bf2f(h1));
    int ks = k >> 5, kg = (k >> 3) & 3, j = k & 7;          // j even
    int nf = n >> 4, nl = n & 15;
    int lane = kg * 16 + nl;
    int bhi = ((ks * nfc + nf) * 2 + 0) * 512 + lane * 8 + j;
    int blo = ((ks * nfc + nf) * 2 + 1) * 512 + lane * 8 + j;
    *(unsigned*)&wf[bhi] = (unsigned)h0 | ((unsigned)h1 << 16);
    *(unsigned*)&wf[blo] = (unsigned)l0 | ((unsigned)l1 << 16);
}

// ================= MFMA projection GEMM, layers 1/2 =================

template <bool RELU_IN>
__global__ __launch_bounds__(256) void k_mfma128(const float* __restrict__ h,
                                                 const u16* __restrict__ wf,
                                                 const float* __restrict__ bias,
                                                 float* __restrict__ outF,
                                                 unsigned* __restrict__ outZ) {
    __shared__ u16 sW[16384];   // 32 KB: 32 frags x 64 lanes x 16B
    int t = threadIdx.x;
    {
        const uint4* g = (const uint4*)wf;
        uint4* s = (uint4*)sW;
#pragma unroll
        for (int i = 0; i < 8; ++i) s[t + i * 256] = g[t + i * 256];
    }
    __syncthreads();

    int lane = t & 63, wid = t >> 6;
    int nl = lane & 15, kg = lane >> 4;
    int rowbase = blockIdx.x * 64 + wid * 16;
    int node = rowbase + nl;
    bool nv = node < N_NODES;
    const float* hp = h + (size_t)node * 64 + kg * 8;

    f32x4 acc[8];
#pragma unroll
    for (int i = 0; i < 8; ++i) acc[i] = (f32x4){0.f, 0.f, 0.f, 0.f};

#pragma unroll
    for (int ks = 0; ks < 2; ++ks) {
        float4 a0, a1;
        if (nv) {
            a0 = *(const float4*)(hp + ks * 32);
            a1 = *(const float4*)(hp + ks * 32 + 4);
        } else {
            a0 = make_float4(0.f, 0.f, 0.f, 0.f);
            a1 = a0;
        }
        float av[8] = {a0.x, a0.y, a0.z, a0.w, a1.x, a1.y, a1.z, a1.w};
        bf16x8 ah, al;
#pragma unroll
        for (int j = 0; j < 8; ++j) {
            float v = av[j];
            if (RELU_IN) v = fmaxf(v, 0.f);
            u16 hb = f2bf(v);
            ah[j] = (short)hb;
            al[j] = (short)f2bf(v - bf2f(hb));
        }
#pragma unroll
        for (int nf = 0; nf < 8; ++nf) {
            bf16x8 wh = *(const bf16x8*)&sW[((ks * 8 + nf) * 2 + 0) * 512 + lane * 8];
            bf16x8 wl = *(const bf16x8*)&sW[((ks * 8 + nf) * 2 + 1) * 512 + lane * 8];
            acc[nf] = __builtin_amdgcn_mfma_f32_16x16x32_bf16(ah, wh, acc[nf], 0, 0, 0);
            acc[nf] = __builtin_amdgcn_mfma_f32_16x16x32_bf16(al, wh, acc[nf], 0, 0, 0);
            acc[nf] = __builtin_amdgcn_mfma_f32_16x16x32_bf16(ah, wl, acc[nf], 0, 0, 0);
        }
    }

    // D layout: col = lane&15, row_in_frag = kg*4 + r  (m89-verified)
#pragma unroll
    for (int nf = 0; nf < 4; ++nf) {            // F half, f32 + bias
        int col = nf * 16 + nl;
        float b = bias[col];
#pragma unroll
        for (int r = 0; r < 4; ++r) {
            int row = rowbase + kg * 4 + r;
            if (row < N_NODES) outF[(size_t)row * 64 + col] = acc[nf][r] + b;
        }
    }
#pragma unroll
    for (int nf = 4; nf < 8; ++nf) {            // Z half, pack bf16 pairs via shfl
        int zc = nf * 16 + nl - 64;
#pragma unroll
        for (int r = 0; r < 4; ++r) {
            float v = acc[nf][r];
            float p = __shfl_xor(v, 1);         // partner col (nl^1), same row
            int row = rowbase + kg * 4 + r;
            if (!(nl & 1) && row < N_NODES)
                outZ[(size_t)row * 32 + (zc >> 1)] = (unsigned)f2bf(v) | ((unsigned)f2bf(p) << 16);
        }
    }
}

// ================= MFMA projection, layer 3 (32 cols: 16 self+bias, 16 neigh) =================

__global__ __launch_bounds__(256) void k_mfma32(const float* __restrict__ h,
                                                const u16* __restrict__ wf,
                                                const float* __restrict__ bias,
                                                float* __restrict__ wbuf,
                                                float* __restrict__ zbuf) {
    __shared__ u16 sW[4096];    // 8 KB
    int t = threadIdx.x;
    {
        const uint4* g = (const uint4*)wf;
        uint4* s = (uint4*)sW;
        s[t] = g[t];
        s[t + 256] = g[t + 256];
    }
    __syncthreads();

    int lane = t & 63, wid = t >> 6;
    int nl = lane & 15, kg = lane >> 4;
    int rowbase = blockIdx.x * 64 + wid * 16;
    int node = rowbase + nl;
    bool nv = node < N_NODES;
    const float* hp = h + (size_t)node * 64 + kg * 8;

    f32x4 acc[2];
    acc[0] = (f32x4){0.f, 0.f, 0.f, 0.f};
    acc[1] = acc[0];

#pragma unroll
    for (int ks = 0; ks < 2; ++ks) {
        float4 a0, a1;
        if (nv) {
            a0 = *(const float4*)(hp + ks * 32);
            a1 = *(const float4*)(hp + ks * 32 + 4);
        } else {
            a0 = make_float4(0.f, 0.f, 0.f, 0.f);
            a1 = a0;
        }
        float av[8] = {a0.x, a0.y, a0.z, a0.w, a1.x, a1.y, a1.z, a1.w};
        bf16x8 ah, al;
#pragma unroll
        for (int j = 0; j < 8; ++j) {
            float v = fmaxf(av[j], 0.f);        // layer-3 input is relu(h2)
            u16 hb = f2bf(v);
            ah[j] = (short)hb;
            al[j] = (short)f2bf(v - bf2f(hb));
        }
#pragma unroll
        for (int nf = 0; nf < 2; ++nf) {
            bf16x8 wh = *(const bf16x8*)&sW[((ks * 2 + nf) * 2 + 0) * 512 + lane * 8];
            bf16x8 wl = *(const bf16x8*)&sW[((ks * 2 + nf) * 2 + 1) * 512 + lane * 8];
            acc[nf] = __builtin_amdgcn_mfma_f32_16x16x32_bf16(ah, wh, acc[nf], 0, 0, 0);
            acc[nf] = __builtin_amdgcn_mfma_f32_16x16x32_bf16(al, wh, acc[nf], 0, 0, 0);
            acc[nf] = __builtin_amdgcn_mfma_f32_16x16x32_bf16(ah, wl, acc[nf], 0, 0, 0);
        }
    }

    float b = bias[nl];
#pragma unroll
    for (int r = 0; r < 4; ++r) {
        int row = rowbase + kg * 4 + r;
        if (row < N_NODES) {
            wbuf[(size_t)row * 16 + nl] = acc[0][r] + b;   // self + bias
            zbuf[(size_t)row * 16 + nl] = acc[1][r];       // neigh projection
        }
    }
}

// ================= Bucket gather, layers 1/2 (bf16 z, 64 feats) =================
// One block per 128-node bucket; edges consumed straight from bucket-contiguous
// `packed`. Accumulate into LDS acc[128][67] via ds_add_f32 (odd stride kills the
// even-bank pileup); degree counted on the fly; epilogue is a fully-coalesced
// contiguous `out +=` over the bucket's rows.

__global__ __launch_bounds__(512, 8) void k_bgather64(const unsigned int* __restrict__ packed,
                                                      const int* __restrict__ bucket_base,
                                                      const unsigned int* __restrict__ z,
                                                      float* __restrict__ out) {
    __shared__ float acc[128 * 67];
    __shared__ float sinv[128];
    __shared__ int cnt[128];

    int t = threadIdx.x, b = blockIdx.x;
    for (int i = t; i < 128 * 67; i += 512) acc[i] = 0.f;
    if (t < 128) cnt[t] = 0;
    __syncthreads();

    int eb = bucket_base[b];
    int ee = bucket_base[b + 1];
    int w = t >> 6, lane = t & 63;
    int sub = lane >> 5, f = lane & 31;

    for (int e = eb + w * 2 + sub; e < ee; e += 16) {
        unsigned p = packed[e];
        int d = (int)(p >> 17);
        int s = (int)(p & 0x1FFFFu);
        unsigned dv = z[(size_t)s * 32 + f];
        float lo = __uint_as_float(dv << 16);
        float hi = __uint_as_float(dv & 0xffff0000u);
        unsafeAtomicAdd(&acc[d * 67 + 2 * f], lo);
        unsafeAtomicAdd(&acc[d * 67 + 2 * f + 1], hi);
        if (f == 0) atomicAdd(&cnt[d], 1);
    }
    __syncthreads();
    if (t < 128) sinv[t] = 1.f / fmaxf((float)cnt[t], 1.f);
    __syncthreads();

    int node0 = b << B_SHIFT;
#pragma unroll
    for (int i = 0; i < 16; ++i) {
        int idx = i * 512 + t;          // 0..8191
        int nd = idx >> 6, ft = idx & 63;
        int row = node0 + nd;
        if (row < N_NODES)
            out[(size_t)row * 64 + ft] += acc[nd * 67 + ft] * sinv[nd];
    }
}

// ================= Bucket gather, layer 3 (f32 z, 16 feats) =================

__global__ __launch_bounds__(512, 8) void k_bgather16(const unsigned int* __restrict__ packed,
                                                      const int* __restrict__ bucket_base,
                                                      const float* __restrict__ zbuf,
                                                      float* __restrict__ out) {
    __shared__ float acc[128 * 17];
    __shared__ float sinv[128];
    __shared__ int cnt[128];

    int t = threadIdx.x, b = blockIdx.x;
    for (int i = t; i < 128 * 17; i += 512) acc[i] = 0.f;
    if (t < 128) cnt[t] = 0;
    __syncthreads();

    int eb = bucket_base[b];
    int ee = bucket_base[b + 1];
    int w = t >> 6, lane = t & 63;
    int sub = lane >> 4, f = lane & 15;

    for (int e = eb + w * 4 + sub; e < ee; e += 32) {
        unsigned p = packed[e];
        int d = (int)(p >> 17);
        int s = (int)(p & 0x1FFFFu);
        float v = zbuf[(size_t)s * 16 + f];
        unsafeAtomicAdd(&acc[d * 17 + f], v);
        if (f == 0) atomicAdd(&cnt[d], 1);
    }
    __syncthreads();
    if (t < 128) sinv[t] = 1.f / fmaxf((float)cnt[t], 1.f);
    __syncthreads();

    int node0 = b << B_SHIFT;
#pragma unroll
    for (int i = 0; i < 4; ++i) {
        int idx = i * 512 + t;          // 0..2047
        int nd = idx >> 4, ft = idx & 15;
        int row = node0 + nd;
        if (row < N_NODES)
            out[(size_t)row * 16 + ft] += acc[nd * 17 + ft] * sinv[nd];
    }
}

// ---------------- launch ----------------

extern "C" void kernel_launch(void* const* d_in, const int* in_sizes, int n_in,
                              void* d_out, int out_size, void* d_ws, size_t ws_size,
                              hipStream_t stream) {
    const float* feat = (const float*)d_in[0];
    const int* ei = (const int*)d_in[1];
    const int* src = ei;
    const int* dst = ei + N_EDGES;
    const float* Ws0 = (const float*)d_in[2];
    const float* Wn0 = (const float*)d_in[3];
    const float* b0  = (const float*)d_in[4];
    const float* Ws1 = (const float*)d_in[5];
    const float* Wn1 = (const float*)d_in[6];
    const float* b1  = (const float*)d_in[7];
    const float* Ws2 = (const float*)d_in[8];
    const float* Wn2 = (const float*)d_in[9];
    const float* b2  = (const float*)d_in[10];

    float* out = (float*)d_out;
    float* out_h3 = out;                                 // [N,16]
    float* out_e0 = out + (size_t)N_NODES * 16;          // [N,64]  pre-relu h1
    float* out_e1 = out + (size_t)N_NODES * (16 + 64);   // [N,64]  pre-relu h2

    char* ws = (char*)d_ws;
    size_t off = 0;
    auto alloc = [&](size_t bytes) -> void* {
        void* p = ws + off;
        off = (off + bytes + 255) & ~(size_t)255;
        return p;
    };
    int* bh          = (int*)alloc((size_t)NBLK * NBUCK * sizeof(int));   // 800 KB
    int* total       = (int*)alloc(NBUCK * sizeof(int));
    int* bucket_base = (int*)alloc((NBUCK + 1) * sizeof(int));
    unsigned int* packed = (unsigned int*)alloc(N_EDGES * sizeof(int));   // 6.4 MB (alive to the end)
    unsigned int* zb = (unsigned int*)alloc((size_t)N_NODES * 32 * sizeof(unsigned)); // 12.8 MB
    float* zbuf3     = (float*)alloc((size_t)N_NODES * 16 * sizeof(float));           // 6.4 MB
    u16* wf0         = (u16*)alloc(16384 * sizeof(u16));  // layer-1 W frags hi/lo (32 KB)
    u16* wf1         = (u16*)alloc(16384 * sizeof(u16));  // layer-2
    u16* wf2         = (u16*)alloc(4096 * sizeof(u16));   // layer-3 (8 KB)
    (void)ws_size;

    k_wprep<<<36, 256, 0, stream>>>(Ws0, Wn0, Ws1, Wn1, Ws2, Wn2, wf0, wf1, wf2);

    q1_hist<<<NBLK, 512, 0, stream>>>(dst, bh, N_EDGES);
    q2_colscan<<<NBUCK, 256, 0, stream>>>(bh, total);
    q3_scan<<<1, 1024, 0, stream>>>(total, bucket_base, N_EDGES);
    q4_scatter<<<NBLK, 512, 0, stream>>>(src, dst, bh, bucket_base, packed, N_EDGES);

    const int GT = (N_NODES + 63) / 64;   // 1563 tiles

    // layer 1
    k_mfma128<false><<<GT, 256, 0, stream>>>(feat, wf0, b0, out_e0, zb);
    k_bgather64<<<NBUCK, 512, 0, stream>>>(packed, bucket_base, zb, out_e0);
    // layer 2
    k_mfma128<true><<<GT, 256, 0, stream>>>(out_e0, wf1, b1, out_e1, zb);
    k_bgather64<<<NBUCK, 512, 0, stream>>>(packed, bucket_base, zb, out_e1);
    // layer 3
    k_mfma32<<<GT, 256, 0, stream>>>(out_e1, wf2, b2, out_h3, zbuf3);
    k_bgather16<<<NBUCK, 512, 0, stream>>>(packed, bucket_base, zbuf3, out_h3);
}

// Round 5
// 296.492 us; speedup vs baseline: 5.7932x; 5.7932x over previous
//
#include <hip/hip_runtime.h>
#include <hip/hip_bf16.h>

typedef __hip_bfloat16 bf16;
typedef unsigned short u16;
typedef __attribute__((ext_vector_type(8))) short bf16x8;   // 8 bf16 in 4 VGPRs (MFMA A/B frag)
typedef __attribute__((ext_vector_type(4))) float f32x4;    // MFMA C/D frag

#define N_NODES 100000
#define N_EDGES 1600000
#define NBUCK 391           // ceil(N_NODES/256), bucket = dst >> 8
#define NBLK 512            // edge-chunk blocks for hist/scatter (must match q1/q4/q2)

static __device__ __forceinline__ u16 f2bf(float x) {
    bf16 h = (bf16)x;
    return *reinterpret_cast<u16*>(&h);
}
static __device__ __forceinline__ float bf2f(u16 b) {
    unsigned u = ((unsigned)b) << 16;
    return __uint_as_float(u);
}

// ================= CSR build: deterministic bucket sort =================
// Round-2 lesson: global-atomic scatter = 16x write amplification (4B random
// writes across XCD L2s). Round-4 lesson: per-edge LDS atomics (ds_add_f32)
// cost ~250 cyc/instr under conflict -> 23x regression; NEVER put an LDS
// atomic on the per-edge critical path. This two-level bucket sort keeps
// per-(block,bucket) writes in contiguous 32B runs (bounded ~2x write amp)
// and its LDS atomics are histogram/cursor only (one per edge, hidden by
// occupancy). Grid shape: NBLK=512 x 512thr (2 blk/CU), p4 at 1024thr.

__global__ __launch_bounds__(512) void q1_hist(const int* __restrict__ dst,
                                               int* __restrict__ bh, int nE) {
    __shared__ int hist[NBUCK];
    int t = threadIdx.x, b = blockIdx.x;
    for (int i = t; i < NBUCK; i += 512) hist[i] = 0;
    __syncthreads();
    int chunk = (nE + NBLK - 1) / NBLK;
    int lo = b * chunk, hi = min(nE, lo + chunk);
    for (int e = lo + t; e < hi; e += 512) atomicAdd(&hist[dst[e] >> 8], 1);
    __syncthreads();
    for (int i = t; i < NBUCK; i += 512) bh[b * NBUCK + i] = hist[i];
}

// exclusive column scan over the NBLK chunk-blocks (threads = NBLK = 512)
__global__ __launch_bounds__(512) void q2_colscan(int* __restrict__ bh,
                                                  int* __restrict__ total) {
    __shared__ int s[512];
    int i = blockIdx.x;       // bucket
    int b = threadIdx.x;      // chunk-block
    int val = bh[b * NBUCK + i];
    s[b] = val;
    __syncthreads();
    for (int off = 1; off < 512; off <<= 1) {
        int x = (b >= off) ? s[b - off] : 0;
        __syncthreads();
        if (b >= off) s[b] += x;
        __syncthreads();
    }
    bh[b * NBUCK + i] = s[b] - val;        // exclusive over blocks
    if (b == 511) total[i] = s[511];
}

__global__ __launch_bounds__(512) void q3_scan(const int* __restrict__ total,
                                               int* __restrict__ bucket_base, int nE) {
    __shared__ int s[512];
    int t = threadIdx.x;
    int val = (t < NBUCK) ? total[t] : 0;
    s[t] = val;
    __syncthreads();
    for (int off = 1; off < 512; off <<= 1) {
        int x = (t >= off) ? s[t - off] : 0;
        __syncthreads();
        if (t >= off) s[t] += x;
        __syncthreads();
    }
    if (t < NBUCK) bucket_base[t] = s[t] - val;
    if (t == 0) bucket_base[NBUCK] = nE;
}

__global__ __launch_bounds__(512) void q4_scatter(const int* __restrict__ src,
                                                  const int* __restrict__ dst,
                                                  const int* __restrict__ bh,
                                                  const int* __restrict__ bucket_base,
                                                  unsigned int* __restrict__ packed, int nE) {
    __shared__ int cur[NBUCK];
    int t = threadIdx.x, b = blockIdx.x;
    for (int i = t; i < NBUCK; i += 512)
        cur[i] = bucket_base[i] + bh[b * NBUCK + i];
    __syncthreads();
    int chunk = (nE + NBLK - 1) / NBLK;
    int lo = b * chunk, hi = min(nE, lo + chunk);
    for (int e = lo + t; e < hi; e += 512) {
        int d = dst[e];
        int pos = atomicAdd(&cur[d >> 8], 1);
        packed[pos] = ((unsigned int)(d & 255) << 17) | (unsigned int)src[e];
    }
}

__global__ __launch_bounds__(1024) void p4_build(const unsigned int* __restrict__ packed,
                                                 const int* __restrict__ bucket_base,
                                                 int* __restrict__ rowptr,
                                                 int* __restrict__ csr, int nN, int nE) {
    __shared__ int cnt[256];
    __shared__ int s[256];
    __shared__ int curs[256];
    int b = blockIdx.x;
    int t = threadIdx.x;
    int node0 = b << 8;
    int ebase = bucket_base[b];
    int eend  = bucket_base[b + 1];

    if (t < 256) cnt[t] = 0;
    __syncthreads();
    for (int e = ebase + t; e < eend; e += 1024)
        atomicAdd(&cnt[packed[e] >> 17], 1);
    __syncthreads();
    int val = (t < 256) ? cnt[t] : 0;
    if (t < 256) s[t] = val;
    __syncthreads();
    for (int off = 1; off < 256; off <<= 1) {
        int x = (t < 256 && t >= off) ? s[t - off] : 0;
        __syncthreads();
        if (t < 256 && t >= off) s[t] += x;
        __syncthreads();
    }
    if (t < 256) {
        int excl = s[t] - val;
        int node = node0 + t;
        if (node < nN) rowptr[node] = ebase + excl;
        curs[t] = ebase + excl;
    }
    if (b == gridDim.x - 1 && t == 0) rowptr[nN] = nE;
    __syncthreads();
    for (int e = ebase + t; e < eend; e += 1024) {
        unsigned int p = packed[e];
        int d = p >> 17;
        int pos = atomicAdd(&curs[d], 1);
        csr[pos] = (int)(p & 0x1FFFFu);
    }
}

// ================= Weight pre-fragmentation for MFMA =================
// W' = [Ws | Wn] combined, [64 k][2*ncol n], split into bf16 hi/lo:
//   w = wh + wl  (3-pass GEMM ah@wh + al@wh + ah@wl -> f32-grade accuracy).
// Fragment order for mfma_f32_16x16x32_bf16 B-operand; see round-0 notes.

__global__ __launch_bounds__(256) void k_wprep(const float* __restrict__ Ws0, const float* __restrict__ Wn0,
                                               const float* __restrict__ Ws1, const float* __restrict__ Wn1,
                                               const float* __restrict__ Ws2, const float* __restrict__ Wn2,
                                               u16* __restrict__ wf0, u16* __restrict__ wf1,
                                               u16* __restrict__ wf2) {
    int id = blockIdx.x * 256 + threadIdx.x;   // 0..9215
    const float *Ws, *Wn;
    u16* wf;
    int ncol, nfc;
    if (id < 4096)       { Ws = Ws0; Wn = Wn0; wf = wf0; ncol = 64; nfc = 8; }
    else if (id < 8192)  { id -= 4096; Ws = Ws1; Wn = Wn1; wf = wf1; ncol = 64; nfc = 8; }
    else if (id < 9216)  { id -= 8192; Ws = Ws2; Wn = Wn2; wf = wf2; ncol = 16; nfc = 2; }
    else return;
    int kp = id / (2 * ncol);       // 0..31 k-pair
    int n  = id % (2 * ncol);
    int k  = kp * 2;
    float w0 = (n < ncol) ? Ws[k * ncol + n]       : Wn[k * ncol + (n - ncol)];
    float w1 = (n < ncol) ? Ws[(k + 1) * ncol + n] : Wn[(k + 1) * ncol + (n - ncol)];
    u16 h0 = f2bf(w0), h1 = f2bf(w1);
    u16 l0 = f2bf(w0 - bf2f(h0)), l1 = f2bf(w1 - bf2f(h1));
    int ks = k >> 5, kg = (k >> 3) & 3, j = k & 7;          // j even
    int nf = n >> 4, nl = n & 15;
    int lane = kg * 16 + nl;
    int bhi = ((ks * nfc + nf) * 2 + 0) * 512 + lane * 8 + j;
    int blo = ((ks * nfc + nf) * 2 + 1) * 512 + lane * 8 + j;
    *(unsigned*)&wf[bhi] = (unsigned)h0 | ((unsigned)h1 << 16);
    *(unsigned*)&wf[blo] = (unsigned)l0 | ((unsigned)l1 << 16);
}

// ================= MFMA projection GEMM, layers 1/2 =================

template <bool RELU_IN>
__global__ __launch_bounds__(256) void k_mfma128(const float* __restrict__ h,
                                                 const u16* __restrict__ wf,
                                                 const float* __restrict__ bias,
                                                 float* __restrict__ outF,
                                                 unsigned* __restrict__ outZ) {
    __shared__ u16 sW[16384];   // 32 KB: 32 frags x 64 lanes x 16B
    int t = threadIdx.x;
    {
        const uint4* g = (const uint4*)wf;
        uint4* s = (uint4*)sW;
#pragma unroll
        for (int i = 0; i < 8; ++i) s[t + i * 256] = g[t + i * 256];
    }
    __syncthreads();

    int lane = t & 63, wid = t >> 6;
    int nl = lane & 15, kg = lane >> 4;
    int rowbase = blockIdx.x * 64 + wid * 16;
    int node = rowbase + nl;
    bool nv = node < N_NODES;
    const float* hp = h + (size_t)node * 64 + kg * 8;

    f32x4 acc[8];
#pragma unroll
    for (int i = 0; i < 8; ++i) acc[i] = (f32x4){0.f, 0.f, 0.f, 0.f};

#pragma unroll
    for (int ks = 0; ks < 2; ++ks) {
        float4 a0, a1;
        if (nv) {
            a0 = *(const float4*)(hp + ks * 32);
            a1 = *(const float4*)(hp + ks * 32 + 4);
        } else {
            a0 = make_float4(0.f, 0.f, 0.f, 0.f);
            a1 = a0;
        }
        float av[8] = {a0.x, a0.y, a0.z, a0.w, a1.x, a1.y, a1.z, a1.w};
        bf16x8 ah, al;
#pragma unroll
        for (int j = 0; j < 8; ++j) {
            float v = av[j];
            if (RELU_IN) v = fmaxf(v, 0.f);
            u16 hb = f2bf(v);
            ah[j] = (short)hb;
            al[j] = (short)f2bf(v - bf2f(hb));
        }
#pragma unroll
        for (int nf = 0; nf < 8; ++nf) {
            bf16x8 wh = *(const bf16x8*)&sW[((ks * 8 + nf) * 2 + 0) * 512 + lane * 8];
            bf16x8 wl = *(const bf16x8*)&sW[((ks * 8 + nf) * 2 + 1) * 512 + lane * 8];
            acc[nf] = __builtin_amdgcn_mfma_f32_16x16x32_bf16(ah, wh, acc[nf], 0, 0, 0);
            acc[nf] = __builtin_amdgcn_mfma_f32_16x16x32_bf16(al, wh, acc[nf], 0, 0, 0);
            acc[nf] = __builtin_amdgcn_mfma_f32_16x16x32_bf16(ah, wl, acc[nf], 0, 0, 0);
        }
    }

    // D layout: col = lane&15, row_in_frag = kg*4 + r  (m89-verified)
#pragma unroll
    for (int nf = 0; nf < 4; ++nf) {            // F half, f32 + bias
        int col = nf * 16 + nl;
        float b = bias[col];
#pragma unroll
        for (int r = 0; r < 4; ++r) {
            int row = rowbase + kg * 4 + r;
            if (row < N_NODES) outF[(size_t)row * 64 + col] = acc[nf][r] + b;
        }
    }
#pragma unroll
    for (int nf = 4; nf < 8; ++nf) {            // Z half, pack bf16 pairs via shfl
        int zc = nf * 16 + nl - 64;
#pragma unroll
        for (int r = 0; r < 4; ++r) {
            float v = acc[nf][r];
            float p = __shfl_xor(v, 1);         // partner col (nl^1), same row
            int row = rowbase + kg * 4 + r;
            if (!(nl & 1) && row < N_NODES)
                outZ[(size_t)row * 32 + (zc >> 1)] = (unsigned)f2bf(v) | ((unsigned)f2bf(p) << 16);
        }
    }
}

// ================= MFMA projection, layer 3 (32 cols: 16 self+bias, 16 neigh) =================

__global__ __launch_bounds__(256) void k_mfma32(const float* __restrict__ h,
                                                const u16* __restrict__ wf,
                                                const float* __restrict__ bias,
                                                float* __restrict__ wbuf,
                                                float* __restrict__ zbuf) {
    __shared__ u16 sW[4096];    // 8 KB
    int t = threadIdx.x;
    {
        const uint4* g = (const uint4*)wf;
        uint4* s = (uint4*)sW;
        s[t] = g[t];
        s[t + 256] = g[t + 256];
    }
    __syncthreads();

    int lane = t & 63, wid = t >> 6;
    int nl = lane & 15, kg = lane >> 4;
    int rowbase = blockIdx.x * 64 + wid * 16;
    int node = rowbase + nl;
    bool nv = node < N_NODES;
    const float* hp = h + (size_t)node * 64 + kg * 8;

    f32x4 acc[2];
    acc[0] = (f32x4){0.f, 0.f, 0.f, 0.f};
    acc[1] = acc[0];

#pragma unroll
    for (int ks = 0; ks < 2; ++ks) {
        float4 a0, a1;
        if (nv) {
            a0 = *(const float4*)(hp + ks * 32);
            a1 = *(const float4*)(hp + ks * 32 + 4);
        } else {
            a0 = make_float4(0.f, 0.f, 0.f, 0.f);
            a1 = a0;
        }
        float av[8] = {a0.x, a0.y, a0.z, a0.w, a1.x, a1.y, a1.z, a1.w};
        bf16x8 ah, al;
#pragma unroll
        for (int j = 0; j < 8; ++j) {
            float v = fmaxf(av[j], 0.f);        // layer-3 input is relu(h2)
            u16 hb = f2bf(v);
            ah[j] = (short)hb;
            al[j] = (short)f2bf(v - bf2f(hb));
        }
#pragma unroll
        for (int nf = 0; nf < 2; ++nf) {
            bf16x8 wh = *(const bf16x8*)&sW[((ks * 2 + nf) * 2 + 0) * 512 + lane * 8];
            bf16x8 wl = *(const bf16x8*)&sW[((ks * 2 + nf) * 2 + 1) * 512 + lane * 8];
            acc[nf] = __builtin_amdgcn_mfma_f32_16x16x32_bf16(ah, wh, acc[nf], 0, 0, 0);
            acc[nf] = __builtin_amdgcn_mfma_f32_16x16x32_bf16(al, wh, acc[nf], 0, 0, 0);
            acc[nf] = __builtin_amdgcn_mfma_f32_16x16x32_bf16(ah, wl, acc[nf], 0, 0, 0);
        }
    }

    float b = bias[nl];
#pragma unroll
    for (int r = 0; r < 4; ++r) {
        int row = rowbase + kg * 4 + r;
        if (row < N_NODES) {
            wbuf[(size_t)row * 16 + nl] = acc[0][r] + b;   // self + bias
            zbuf[(size_t)row * 16 + nl] = acc[1][r];       // neigh projection
        }
    }
}

// ===== Gather (layers 1/2, bf16 z): out[v] += segmean(z[src]) =====
// CSR-walk, wave per node, accumulate in registers (round-4 lesson: this
// structure beats LDS-atomic bucket accumulation by >20x).

__global__ __launch_bounds__(256, 8) void k_gather64b(const int* __restrict__ rowptr,
                                                      const int* __restrict__ csr,
                                                      const unsigned int* __restrict__ z,
                                                      float* __restrict__ out) {
    int t = threadIdx.x;
    int w = t >> 6, lane = t & 63;
    int sub = lane >> 5;
    int f = lane & 31;

    for (int v = blockIdx.x * 4 + w; v < N_NODES; v += gridDim.x * 4) {
        int beg = rowptr[v];
        int end = rowptr[v + 1];
        float ax = 0.f, ay = 0.f;

        for (int e0 = beg; e0 < end; e0 += 64) {
            int n = end - e0; if (n > 64) n = 64;
            int ids = (e0 + lane < end) ? csr[e0 + lane] : 0;
            int full = n >> 1;
            int i = 0;
            for (; i + 4 <= full; i += 4) {
                int r0 = __shfl(ids, 2 * i + sub);
                int r1 = __shfl(ids, 2 * i + 2 + sub);
                int r2 = __shfl(ids, 2 * i + 4 + sub);
                int r3 = __shfl(ids, 2 * i + 6 + sub);
                unsigned d0 = z[(size_t)r0 * 32 + f];
                unsigned d1 = z[(size_t)r1 * 32 + f];
                unsigned d2 = z[(size_t)r2 * 32 + f];
                unsigned d3 = z[(size_t)r3 * 32 + f];
                ax += __uint_as_float(d0 << 16); ay += __uint_as_float(d0 & 0xffff0000u);
                ax += __uint_as_float(d1 << 16); ay += __uint_as_float(d1 & 0xffff0000u);
                ax += __uint_as_float(d2 << 16); ay += __uint_as_float(d2 & 0xffff0000u);
                ax += __uint_as_float(d3 << 16); ay += __uint_as_float(d3 & 0xffff0000u);
            }
            for (; i < full; ++i) {
                int r = __shfl(ids, 2 * i + sub);
                unsigned d = z[(size_t)r * 32 + f];
                ax += __uint_as_float(d << 16); ay += __uint_as_float(d & 0xffff0000u);
            }
            int rt = __shfl(ids, n - 1);
            if ((n & 1) && sub == 0) {
                unsigned d = z[(size_t)rt * 32 + f];
                ax += __uint_as_float(d << 16); ay += __uint_as_float(d & 0xffff0000u);
            }
        }

        ax += __shfl_xor(ax, 32);
        ay += __shfl_xor(ay, 32);
        if (sub == 0) {
            float inv = 1.f / fmaxf((float)(end - beg), 1.f);
            float2* op = (float2*)(out + (size_t)v * 64) + f;
            float2 cur = *op;
            cur.x += ax * inv;
            cur.y += ay * inv;
            *op = cur;
        }
    }
}

// ===== Layer-3 gather =====

__global__ __launch_bounds__(256, 8) void k_gather3(const int* __restrict__ rowptr,
                                                    const int* __restrict__ csr,
                                                    const float* __restrict__ zbuf,
                                                    const float* __restrict__ wbuf,
                                                    float* __restrict__ out) {
    int t = threadIdx.x;
    int w = t >> 6;
    int lane = t & 63;
    int g = lane >> 4;
    int j = lane & 15;

    for (int v = blockIdx.x * 4 + w; v < N_NODES; v += gridDim.x * 4) {
        int beg = rowptr[v];
        int end = rowptr[v + 1];
        float acc = 0.f;
        int e = beg + g;
        for (; e + 4 < end; e += 8) {
            float a0 = zbuf[(size_t)csr[e] * 16 + j];
            float a1 = zbuf[(size_t)csr[e + 4] * 16 + j];
            acc += a0;
            acc += a1;
        }
        if (e < end) acc += zbuf[(size_t)csr[e] * 16 + j];
        acc += __shfl_xor(acc, 16);
        acc += __shfl_xor(acc, 32);
        if (g == 0) {
            float deg = (float)(end - beg);
            out[(size_t)v * 16 + j] = wbuf[(size_t)v * 16 + j] + acc / fmaxf(deg, 1.0f);
        }
    }
}

// ---------------- launch ----------------

extern "C" void kernel_launch(void* const* d_in, const int* in_sizes, int n_in,
                              void* d_out, int out_size, void* d_ws, size_t ws_size,
                              hipStream_t stream) {
    const float* feat = (const float*)d_in[0];
    const int* ei = (const int*)d_in[1];
    const int* src = ei;
    const int* dst = ei + N_EDGES;
    const float* Ws0 = (const float*)d_in[2];
    const float* Wn0 = (const float*)d_in[3];
    const float* b0  = (const float*)d_in[4];
    const float* Ws1 = (const float*)d_in[5];
    const float* Wn1 = (const float*)d_in[6];
    const float* b1  = (const float*)d_in[7];
    const float* Ws2 = (const float*)d_in[8];
    const float* Wn2 = (const float*)d_in[9];
    const float* b2  = (const float*)d_in[10];

    float* out = (float*)d_out;
    float* out_h3 = out;                                 // [N,16]
    float* out_e0 = out + (size_t)N_NODES * 16;          // [N,64]  pre-relu h1
    float* out_e1 = out + (size_t)N_NODES * (16 + 64);   // [N,64]  pre-relu h2

    char* ws = (char*)d_ws;
    size_t off = 0;
    auto alloc = [&](size_t bytes) -> void* {
        void* p = ws + off;
        off = (off + bytes + 255) & ~(size_t)255;
        return p;
    };
    int* bh          = (int*)alloc((size_t)NBLK * NBUCK * sizeof(int));   // 800 KB
    int* total       = (int*)alloc(NBUCK * sizeof(int));
    int* bucket_base = (int*)alloc((NBUCK + 1) * sizeof(int));
    int* rowptr      = (int*)alloc((N_NODES + 1) * sizeof(int));
    unsigned int* packed = (unsigned int*)alloc(N_EDGES * sizeof(int));   // 6.4 MB
    int* csr         = (int*)alloc(N_EDGES * sizeof(int));                // 6.4 MB
    unsigned int* zb = (unsigned int*)alloc((size_t)N_NODES * 32 * sizeof(unsigned)); // 12.8 MB
    u16* wf0         = (u16*)alloc(16384 * sizeof(u16));  // layer-1 W frags hi/lo (32 KB)
    u16* wf1         = (u16*)alloc(16384 * sizeof(u16));  // layer-2
    u16* wf2         = (u16*)alloc(4096 * sizeof(u16));   // layer-3 (8 KB)
    // layer-3 z (f32 [N,16] = 6.4 MB) aliases `packed` (dead after p4_build)
    float* zbuf3     = (float*)packed;
    (void)ws_size;

    k_wprep<<<36, 256, 0, stream>>>(Ws0, Wn0, Ws1, Wn1, Ws2, Wn2, wf0, wf1, wf2);

    q1_hist<<<NBLK, 512, 0, stream>>>(dst, bh, N_EDGES);
    q2_colscan<<<NBUCK, 512, 0, stream>>>(bh, total);
    q3_scan<<<1, 512, 0, stream>>>(total, bucket_base, N_EDGES);
    q4_scatter<<<NBLK, 512, 0, stream>>>(src, dst, bh, bucket_base, packed, N_EDGES);
    p4_build<<<NBUCK, 1024, 0, stream>>>(packed, bucket_base, rowptr, csr, N_NODES, N_EDGES);

    const int GT = (N_NODES + 63) / 64;   // 1563 tiles

    // layer 1
    k_mfma128<false><<<GT, 256, 0, stream>>>(feat, wf0, b0, out_e0, zb);
    k_gather64b<<<2048, 256, 0, stream>>>(rowptr, csr, zb, out_e0);
    // layer 2
    k_mfma128<true><<<GT, 256, 0, stream>>>(out_e0, wf1, b1, out_e1, zb);
    k_gather64b<<<2048, 256, 0, stream>>>(rowptr, csr, zb, out_e1);
    // layer 3
    k_mfma32<<<GT, 256, 0, stream>>>(out_e1, wf2, b2, out_h3, zbuf3);
    k_gather3<<<2048, 256, 0, stream>>>(rowptr, csr, zbuf3, out_h3, out_h3);
}